// Round 3
// baseline (218.172 us; speedup 1.0000x reference)
//
#include <hip/hip_runtime.h>
#include <hip/hip_fp16.h>

typedef _Float16 half4 __attribute__((ext_vector_type(4)));
typedef float floatx4 __attribute__((ext_vector_type(4)));

#define LDSW 136  // f16 elements per LDS row (128 + 8 pad): 4-way max conflict on b64 reads

// One kernel does both GEMMs: blockIdx.y = 0 -> (Eu,W1,b1)->tu ; 1 -> (Ev,W2,b2)->tv
// Each block: 256 threads = 4 waves; each wave computes 64 rows x 128 cols.
// MFMA v_mfma_f32_16x16x16f16, K looped 8x16. W staged f32->f16 into LDS.
// A layout: lane holds A[row=lane&15][k=4*(lane>>4)+j]; B: B[k=4*(lane>>4)+j][col=lane&15];
// D: lane holds D[row=4*(lane>>4)+j][col=lane&15]  (measured gfx950 mapping).
__global__ __launch_bounds__(256) void gemm_relu_kernel(
    const float* __restrict__ Xu, const float* __restrict__ Xv,
    const float* __restrict__ W1, const float* __restrict__ W2,
    const float* __restrict__ b1, const float* __restrict__ b2,
    _Float16* __restrict__ OUTu, _Float16* __restrict__ OUTv,
    int Nu, int Nv)
{
  const float* X; const float* W; const float* bias; _Float16* OUT; int N;
  if (blockIdx.y == 0) { X = Xu; W = W1; bias = b1; OUT = OUTu; N = Nu; }
  else                 { X = Xv; W = W2; bias = b2; OUT = OUTv; N = Nv; }

  __shared__ _Float16 Wl[128 * LDSW];

  const int tid = threadIdx.x;
  // Stage W (128x128 f32) into LDS as f16, row-major with stride LDSW.
  for (int c = tid; c < 4096; c += 256) {           // c = float4 chunk index
    floatx4 v = *(const floatx4*)(W + c * 4);
    half4 h;
    h[0] = (_Float16)v[0]; h[1] = (_Float16)v[1];
    h[2] = (_Float16)v[2]; h[3] = (_Float16)v[3];
    const int t = (c * 4) >> 7;                     // W row (= output column index)
    const int k = (c * 4) & 127;
    *(half4*)(&Wl[t * LDSW + k]) = h;               // 8B store, aligned
  }
  __syncthreads();

  const int wave = tid >> 6;
  const int lane = tid & 63;
  const int r16  = lane & 15;   // A-row / D-col / B-col index
  const int g4   = lane >> 4;   // k-group
  const long rowBase = (long)blockIdx.x * 256 + wave * 64;

  float bv[8];
  #pragma unroll
  for (int t = 0; t < 8; ++t) bv[t] = bias[t * 16 + r16];

  for (int grp = 0; grp < 4; ++grp) {
    const long rowA = rowBase + grp * 16 + r16;
    const float* xr = X + (rowA < N ? rowA : 0) * 128;

    floatx4 acc[8];
    #pragma unroll
    for (int t = 0; t < 8; ++t) acc[t] = (floatx4){0.f, 0.f, 0.f, 0.f};

    #pragma unroll
    for (int kk = 0; kk < 8; ++kk) {
      const int kbase = kk * 16 + g4 * 4;
      floatx4 xa = *(const floatx4*)(xr + kbase);   // A[row=r16][kbase..+3], f32
      half4 a;
      a[0] = (_Float16)xa[0]; a[1] = (_Float16)xa[1];
      a[2] = (_Float16)xa[2]; a[3] = (_Float16)xa[3];
      #pragma unroll
      for (int t = 0; t < 8; ++t) {
        // B[k][c] = W[c][k]; c = t*16 + r16, k = kbase..+3
        half4 b = *(const half4*)(&Wl[(t * 16 + r16) * LDSW + kbase]);
        acc[t] = __builtin_amdgcn_mfma_f32_16x16x16f16(a, b, acc[t], 0, 0, 0);
      }
    }

    // D layout: lane holds rows g4*4+j (j=0..3), col = t*16 + r16
    const long rr0 = rowBase + grp * 16 + g4 * 4;
    #pragma unroll
    for (int j = 0; j < 4; ++j) {
      const long rr = rr0 + j;
      if (rr < N) {
        #pragma unroll
        for (int t = 0; t < 8; ++t) {
          float v = acc[t][j] + bv[t];
          v = v > 0.f ? v : 0.f;                    // ReLU
          OUT[rr * 128 + t * 16 + r16] = (_Float16)v;
        }
      }
    }
  }
}

// 16 lanes per edge; each lane loads 8 f16 (16B) from each table (256B/row, coalesced),
// accumulates squared diff in f32, shfl_xor reduce within the 16-lane group.
// Partial last block is safe: e >= E kills whole 16-lane groups, shuffles stay group-intact.
__global__ __launch_bounds__(256) void edge_kernel(
    const _Float16* __restrict__ tu, const _Float16* __restrict__ tv,
    const int* __restrict__ eidx, const float* __restrict__ eval_,
    float* __restrict__ out, int E)
{
  const long t = (long)blockIdx.x * 256 + threadIdx.x;
  const long e = t >> 4;
  const int sub = (int)(t & 15);
  if (e >= E) return;

  const int src = eidx[e];
  const int dst = eidx[E + e];

  floatx4 va = *(const floatx4*)(tu + (long)src * 128 + sub * 8);
  floatx4 vb = *(const floatx4*)(tv + (long)dst * 128 + sub * 8);

  const __half2* ha = (const __half2*)&va;
  const __half2* hb = (const __half2*)&vb;
  float s = 0.f;
  #pragma unroll
  for (int j = 0; j < 4; ++j) {
    float2 fa = __half22float2(ha[j]);
    float2 fb = __half22float2(hb[j]);
    float d0 = fa.x - fb.x;
    float d1 = fa.y - fb.y;
    s += d0 * d0 + d1 * d1;
  }
  #pragma unroll
  for (int off = 1; off < 16; off <<= 1)   // xor 1,2,4,8 within the 16-lane group
    s += __shfl_xor(s, off, 64);

  if (sub == 0) {
    float dist = sqrtf(s);
    float sim  = expf(dist);
    float sig  = 1.f / (1.f + expf(-sim));  // sim >= 1 always; expf(-sim) can't overflow
    out[e] = eval_[e] * sig;
  }
}

extern "C" void kernel_launch(void* const* d_in, const int* in_sizes, int n_in,
                              void* d_out, int out_size, void* d_ws, size_t ws_size,
                              hipStream_t stream) {
  const float* Eu  = (const float*)d_in[0];
  const float* Ev  = (const float*)d_in[1];
  const float* W1  = (const float*)d_in[2];
  const float* b1  = (const float*)d_in[3];
  const float* W2  = (const float*)d_in[4];
  const float* b2  = (const float*)d_in[5];
  const int*  eidx = (const int*)d_in[6];   // harness contract: integer inputs -> const int*
  const float* ev  = (const float*)d_in[7];
  float* out = (float*)d_out;

  const int Nu = in_sizes[0] / 128;
  const int Nv = in_sizes[1] / 128;
  const int E  = in_sizes[7];               // edge_val count == E

  _Float16* tu = (_Float16*)d_ws;           // needs (Nu+Nv)*128*2 = 51.2 MB of ws
  _Float16* tv = tu + (size_t)Nu * 128;

  const int nmax = Nu > Nv ? Nu : Nv;
  dim3 ggrid((nmax + 255) / 256, 2);
  gemm_relu_kernel<<<ggrid, 256, 0, stream>>>(Eu, Ev, W1, W2, b1, b2, tu, tv, Nu, Nv);

  const long ethreads = (long)E * 16;
  const int eblocks = (int)((ethreads + 255) / 256);
  edge_kernel<<<eblocks, 256, 0, stream>>>(tu, tv, eidx, ev, out, E);
}